// Round 6
// baseline (214.781 us; speedup 1.0000x reference)
//
#include <hip/hip_runtime.h>

// Problem: B=8, L=2048, H=256. fp32 in/out.
#define B_ 8
#define L_ 2048
#define H_ 256
#define LOG2E 1.4426950408889634f

typedef _Float16 half8 __attribute__((ext_vector_type(8)));
typedef float f32x4 __attribute__((ext_vector_type(4)));

__device__ __forceinline__ float fast_tanh(float x) {
    const float e2 = __expf(2.f * x);
    return 1.f - 2.f * __builtin_amdgcn_rcpf(e2 + 1.f);
}

// Score in exp2 domain: s2 = (st*m + cm) * LOG2E * base(d).
// Single shared definition: prepass max vs main-loop scores must round
// identically so exp2(s2 - max) <= 1 (fp16-safe P).
__device__ __forceinline__ float score_arg(float st, float cmv, float mv, int d) {
    const float x = fmaf(st, mv, cmv) * LOG2E;
    const float t = (d == 0) ? 0.5f
                             : __builtin_amdgcn_rcpf(__log2f(2.0f + (float)d));
    return x * t;
}

// ---------------------------------------------------------------------------
// prep: one block = 32 rows of text (mat=0) or opin (mat=1). Grid 1024 ->
// 4 blocks/CU (cross-block overlap hides barriers/latency).
// MFMA GEMM rows@W^T (fp16 in, fp32 acc). Wave (rg = 16-row grp, nh = n-half).
// mat=1 emits V^T fp16: vtg[(b*256+h)*2048 + j].
// ---------------------------------------------------------------------------
__global__ __launch_bounds__(256, 4) void prep_kernel(
    const float* __restrict__ opin, const float* __restrict__ text,
    const int* __restrict__ pos_ids,
    const float* __restrict__ Wt, const float* __restrict__ bt,
    const float* __restrict__ Wo, const float* __restrict__ wa,
    const float* __restrict__ ba,
    float* __restrict__ ws_st, float2* __restrict__ ws_cm,
    _Float16* __restrict__ vtg)
{
    __shared__ __align__(16) _Float16 a_lds[2][8][512];   // [rg][kc][frag] 16 KB
    __shared__ __align__(16) _Float16 w_lds[16][512];     // 16 KB, single buffer
    __shared__ float red[2][2][16];                       // [nh][rg][row16]

    const int tid  = threadIdx.x;
    const int lane = tid & 63;
    const int wid  = tid >> 6;
    const int rg   = wid & 1;
    const int nh   = wid >> 1;
    const int em   = lane & 15, quad = lane >> 4;
    const int mat  = blockIdx.x & 1;
    const size_t g0 = (size_t)(blockIdx.x >> 1) * 32;

    const float* __restrict__ src = mat ? opin : text;
    const float* __restrict__ W   = mat ? Wo   : Wt;

    // ---- stage A: 32 rows x 256 k, fp32->fp16, frag-linear ----
#pragma unroll
    for (int i = 0; i < 4; ++i) {
        const int idx = i * 256 + tid;
        const int row = idx >> 5;
        const int k   = (idx & 31) * 8;
        const float4 f0 = *(const float4*)(src + (g0 + row) * 256 + k);
        const float4 f1 = *(const float4*)(src + (g0 + row) * 256 + k + 4);
        half8 h = { (_Float16)f0.x, (_Float16)f0.y, (_Float16)f0.z, (_Float16)f0.w,
                    (_Float16)f1.x, (_Float16)f1.y, (_Float16)f1.z, (_Float16)f1.w };
        *(half8*)&a_lds[row >> 4][k >> 5][((row & 15) + 16 * ((k >> 3) & 3)) * 8] = h;
    }

    // prefetch W chunk 0
    float4 wreg[8];
#pragma unroll
    for (int i = 0; i < 4; ++i) {
        const int idx = i * 256 + tid;
        const int n = idx >> 2, ko = (idx & 3) * 8;
        wreg[2 * i]     = *(const float4*)(W + n * 256 + ko);
        wreg[2 * i + 1] = *(const float4*)(W + n * 256 + ko + 4);
    }
    __syncthreads();   // a_lds ready

    f32x4 acc[8];
#pragma unroll
    for (int nt = 0; nt < 8; ++nt) acc[nt] = (f32x4){0.f, 0.f, 0.f, 0.f};

    for (int kc = 0; kc < 8; ++kc) {
        // write prefetched W chunk (fp16, frag-linear)
#pragma unroll
        for (int i = 0; i < 4; ++i) {
            const int idx = i * 256 + tid;
            const int n = idx >> 2, ko = (idx & 3) * 8;
            const float4 a = wreg[2 * i], c = wreg[2 * i + 1];
            half8 h = { (_Float16)a.x, (_Float16)a.y, (_Float16)a.z, (_Float16)a.w,
                        (_Float16)c.x, (_Float16)c.y, (_Float16)c.z, (_Float16)c.w };
            *(half8*)&w_lds[n >> 4][((n & 15) + 16 * (ko >> 3)) * 8] = h;
        }
        __syncthreads();   // w_lds ready
        if (kc < 7) {
#pragma unroll
            for (int i = 0; i < 4; ++i) {
                const int idx = i * 256 + tid;
                const int n = idx >> 2, ko = (idx & 3) * 8;
                wreg[2 * i]     = *(const float4*)(W + n * 256 + (kc + 1) * 32 + ko);
                wreg[2 * i + 1] = *(const float4*)(W + n * 256 + (kc + 1) * 32 + ko + 4);
            }
        }
        const half8 af = *(const half8*)&a_lds[rg][kc][lane * 8];
#pragma unroll
        for (int nt = 0; nt < 8; ++nt) {
            const half8 bf = *(const half8*)&w_lds[nh * 8 + nt][lane * 8];
            acc[nt] = __builtin_amdgcn_mfma_f32_16x16x32_f16(af, bf, acc[nt], 0, 0, 0);
        }
        __syncthreads();   // all reads done before next overwrite
    }

    // ---- epilogue: rowsum_n( tanh(acc + bt?) * wa ) over this wave's n-half ----
    float rowsum[4] = {0.f, 0.f, 0.f, 0.f};
#pragma unroll
    for (int nt = 0; nt < 8; ++nt) {
        const int col  = nh * 128 + nt * 16 + em;
        const float btv = mat ? 0.f : bt[col];
        const float wav = wa[mat * 256 + col];
#pragma unroll
        for (int r = 0; r < 4; ++r)
            rowsum[r] += fast_tanh(acc[nt][r] + btv) * wav;
    }
#pragma unroll
    for (int r = 0; r < 4; ++r) {
        float s = rowsum[r];
        s += __shfl_xor(s, 1, 64);
        s += __shfl_xor(s, 2, 64);
        s += __shfl_xor(s, 4, 64);
        s += __shfl_xor(s, 8, 64);
        if (em == 0) red[nh][rg][quad * 4 + r] = s;
    }
    __syncthreads();

    if (tid < 32) {
        const float s = red[0][tid >> 4][tid & 15] + red[1][tid >> 4][tid & 15];
        const size_t grow = g0 + tid;
        if (mat == 0) {
            ws_st[grow] = s;
        } else {
            const int p = pos_ids[grow];
            const bool isop = (p==19)|(p==20)|(p==21)|(p==33)|(p==34)|(p==35)|((p>=41)&(p<=46));
            const float mult = isop ? 8.f : 1.f;
            ws_cm[grow] = make_float2((s + ba[0]) * mult, mult);
        }
    }

    // ---- V^T emission (opin blocks): vtg[(b*256+h)*2048 + j] ----
    if (mat == 1) {
        const int h = tid;
        const int kcS = h >> 5, kq = (h >> 3) & 3, jh = h & 7;
        _Float16 vals[32];
#pragma unroll
        for (int r = 0; r < 32; ++r)
            vals[r] = a_lds[r >> 4][kcS][((r & 15) + 16 * kq) * 8 + jh];
        _Float16* dst = vtg + ((size_t)((g0 >> 11) * 256 + h)) * 2048 + (g0 & 2047);
#pragma unroll
        for (int w = 0; w < 4; ++w)
            *(half8*)(dst + w * 8) = *(half8*)&vals[w * 8];
    }
}

// ---------------------------------------------------------------------------
// attn: 256 blocks = (b, 64-row tile), 512 thr. WAVE-SPECIALIZED:
//   waves 0-3 (producers): exact-max prepass share + scores for chunk k+1
//     directly in MFMA A-layout -> dbuf p_lds (dup-free, 16 exp2/lane/chunk).
//   waves 4-7 (consumers): af from p_lds + bf DIRECT FROM GLOBAL (register
//     double-buffer, prefetched 1 chunk ahead) + 32 MFMA for chunk k.
// One barrier per interval; producer VALU overlaps consumer LDS/L2/MFMA.
// No V staging in LDS at all (LDS total ~17 KB).
// ---------------------------------------------------------------------------
__global__ __launch_bounds__(512, 1) void attn_kernel(
    const float* __restrict__ ws_st, const float2* __restrict__ ws_cm,
    const _Float16* __restrict__ vtg, float* __restrict__ out)
{
    __shared__ __align__(16) _Float16 p_lds[2][4][2][512];  // [buf][rt][ks][frag]
    __shared__ float m_tbl[64];
    __shared__ float zrow[64];

    const int tid  = threadIdx.x;
    const int lane = tid & 63;
    const int wid  = tid >> 6;
    const int em   = lane & 15, quad = lane >> 4;
    const int b    = blockIdx.x & 7;          // batch -> XCD L2 locality
    const int i0   = (blockIdx.x >> 3) * 64;

    const bool producer = (wid < 4);
    const int cw = wid - 4;                   // consumer h-quarter

    const _Float16* __restrict__ vb = vtg + (size_t)(b * 256) * 2048;

    // consumer: issue bf(0) prefetch before prepass (latency hidden)
    half8 bfr[2][8];
    if (!producer) {
#pragma unroll
        for (int ht = 0; ht < 4; ++ht)
#pragma unroll
            for (int ks = 0; ks < 2; ++ks) {
                const int h = cw * 64 + ht * 16 + em;
                const int j = ks * 32 + quad * 8;
                bfr[0][ht * 2 + ks] = *(const half8*)(vb + (size_t)h * 2048 + j);
            }
    }

    // ---- exact row-max prepass (all 8 waves; dup-free) ----
    {
        const int prow = wid * 8 + (lane >> 3);
        const int gi_p = i0 + prow;
        const float st_p = ws_st[b * 2048 + gi_p];
        const int jg = (lane & 7) * 8;
        float mx = -3.0e38f;
        for (int t = 0; t < 32; ++t) {
            const int j = t * 64 + jg;
            const float4* cmp = (const float4*)(ws_cm + (size_t)b * 2048 + j);
            const float4 c01 = cmp[0], c23 = cmp[1], c45 = cmp[2], c67 = cmp[3];
            const float cmm[8] = {c01.x, c01.z, c23.x, c23.z, c45.x, c45.z, c67.x, c67.z};
            const float mm[8]  = {c01.y, c01.w, c23.y, c23.w, c45.y, c45.w, c67.y, c67.w};
#pragma unroll
            for (int e = 0; e < 8; ++e) {
                int d = gi_p - (j + e); d = d < 0 ? -d : d;
                mx = fmaxf(mx, score_arg(st_p, cmm[e], mm[e], d));
            }
        }
        mx = fmaxf(mx, __shfl_xor(mx, 1, 64));
        mx = fmaxf(mx, __shfl_xor(mx, 2, 64));
        mx = fmaxf(mx, __shfl_xor(mx, 4, 64));
        if ((lane & 7) == 0) m_tbl[prow] = mx;
    }
    __syncthreads();   // m_tbl ready

    // producer row constants (wave wid owns rows wid*16..+15, lane row = em)
    float st_r = 0.f, mp = 0.f;
    int gi = 0;
    if (producer) {
        const int row = wid * 16 + em;
        gi   = i0 + row;
        st_r = ws_st[b * 2048 + gi];
        mp   = m_tbl[row];
    }
    float zacc = 0.f;

    // producer: compute scores for chunk `kchunk` into p_lds[pbuf][wid][ks]
    auto produce = [&](int kchunk, int pbuf) {
        const int j0 = kchunk * 64;
#pragma unroll
        for (int ks = 0; ks < 2; ++ks) {
            const int jb = j0 + ks * 32 + quad * 8;
            const float4* cmp = (const float4*)(ws_cm + (size_t)b * 2048 + jb);
            const float4 c01 = cmp[0], c23 = cmp[1], c45 = cmp[2], c67 = cmp[3];
            const float cmm[8] = {c01.x, c01.z, c23.x, c23.z, c45.x, c45.z, c67.x, c67.z};
            const float mm[8]  = {c01.y, c01.w, c23.y, c23.w, c45.y, c45.w, c67.y, c67.w};
            const int c0 = gi - jb;
            half8 pv;
#pragma unroll
            for (int e = 0; e < 8; ++e) {
                int d = c0 - e; d = d < 0 ? -d : d;
                const float p = __builtin_exp2f(score_arg(st_r, cmm[e], mm[e], d) - mp);
                zacc += p;
                pv[e] = (_Float16)p;
            }
            *(half8*)&p_lds[pbuf][wid][ks][lane * 8] = pv;
        }
    };

    if (producer) produce(0, 0);
    __syncthreads();   // p_lds[0] ready

    f32x4 acc[4][4];
#pragma unroll
    for (int rt = 0; rt < 4; ++rt)
#pragma unroll
        for (int ht = 0; ht < 4; ++ht) acc[rt][ht] = (f32x4){0.f, 0.f, 0.f, 0.f};

    // ---- main loop: one barrier per interval ----
    for (int kc = 0; kc < 32; ++kc) {
        const int buf = kc & 1;
        if (producer) {
            if (kc < 31) produce(kc + 1, buf ^ 1);
        } else {
            // prefetch bf(kc+1) from global (consumed next interval)
            if (kc < 31) {
#pragma unroll
                for (int ht = 0; ht < 4; ++ht)
#pragma unroll
                    for (int ks = 0; ks < 2; ++ks) {
                        const int h = cw * 64 + ht * 16 + em;
                        const int j = (kc + 1) * 64 + ks * 32 + quad * 8;
                        bfr[buf ^ 1][ht * 2 + ks] = *(const half8*)(vb + (size_t)h * 2048 + j);
                    }
            }
            // af for chunk kc
            half8 af[4][2];
#pragma unroll
            for (int rt = 0; rt < 4; ++rt)
#pragma unroll
                for (int ks = 0; ks < 2; ++ks)
                    af[rt][ks] = *(const half8*)&p_lds[buf][rt][ks][lane * 8];
            // 32 MFMA
#pragma unroll
            for (int ks = 0; ks < 2; ++ks)
#pragma unroll
                for (int ht = 0; ht < 4; ++ht) {
                    const half8 bf = bfr[buf][ht * 2 + ks];
#pragma unroll
                    for (int rt = 0; rt < 4; ++rt)
                        acc[rt][ht] = __builtin_amdgcn_mfma_f32_16x16x32_f16(af[rt][ks], bf, acc[rt][ht], 0, 0, 0);
                }
        }
        __syncthreads();
    }

    // ---- Z finalize (producers own rows) ----
    if (producer) {
        zacc += __shfl_xor(zacc, 16, 64);
        zacc += __shfl_xor(zacc, 32, 64);
        if (quad == 0) zrow[wid * 16 + em] = zacc;
    }
    __syncthreads();

    // ---- epilogue (consumers): C/D row = quad*4+reg, col = em ----
    if (!producer) {
#pragma unroll
        for (int rt = 0; rt < 4; ++rt) {
#pragma unroll
            for (int r = 0; r < 4; ++r) {
                const int rloc = rt * 16 + quad * 4 + r;
                const float rz = 1.0f / zrow[rloc];
                float* op = out + ((size_t)b * 2048 + (i0 + rloc)) * 256 + cw * 64 + em;
#pragma unroll
                for (int ht = 0; ht < 4; ++ht)
                    op[ht * 16] = acc[rt][ht][r] * rz;
            }
        }
    }
}

// ---------------------------------------------------------------------------
extern "C" void kernel_launch(void* const* d_in, const int* in_sizes, int n_in,
                              void* d_out, int out_size, void* d_ws, size_t ws_size,
                              hipStream_t stream) {
    const float* opin  = (const float*)d_in[0];
    const float* text  = (const float*)d_in[1];
    const int* pos_ids = (const int*)d_in[2];
    const float* Wt    = (const float*)d_in[3];
    const float* bt    = (const float*)d_in[4];
    const float* Wo    = (const float*)d_in[5];
    const float* wa    = (const float*)d_in[6];
    const float* ba    = (const float*)d_in[7];
    float* out         = (float*)d_out;

    // workspace: st (64 KB) | cm (128 KB) | vtg fp16 [b*256+h][2048] (8 MB)
    float*  ws_st = (float*)d_ws;
    float2* ws_cm = (float2*)((char*)d_ws + 65536);
    _Float16* vtg = (_Float16*)((char*)d_ws + 65536 + 131072);

    prep_kernel<<<1024, 256, 0, stream>>>(opin, text, pos_ids, Wt, bt, Wo, wa, ba,
                                          ws_st, ws_cm, vtg);
    attn_kernel<<<256, 512, 0, stream>>>(ws_st, ws_cm, vtg, out);
}

// Round 7
// 179.493 us; speedup vs baseline: 1.1966x; 1.1966x over previous
//
#include <hip/hip_runtime.h>

// Problem: B=8, L=2048, H=256. fp32 in/out.
#define B_ 8
#define L_ 2048
#define H_ 256
#define LOG2E 1.4426950408889634f

typedef _Float16 half8 __attribute__((ext_vector_type(8)));
typedef float f32x4 __attribute__((ext_vector_type(4)));

__device__ __forceinline__ float fast_tanh(float x) {
    const float e2 = __expf(2.f * x);
    return 1.f - 2.f * __builtin_amdgcn_rcpf(e2 + 1.f);
}

// Score in exp2 domain: s2 = (st*m + cm) * LOG2E * base(d).
// Single shared definition: prepass max vs main-loop scores must round
// identically so exp2(s2 - max) <= 1 (fp16-safe P).
__device__ __forceinline__ float score_arg(float st, float cmv, float mv, int d) {
    const float x = fmaf(st, mv, cmv) * LOG2E;
    const float t = (d == 0) ? 0.5f
                             : __builtin_amdgcn_rcpf(__log2f(2.0f + (float)d));
    return x * t;
}

// ---------------------------------------------------------------------------
// prep: one block = 32 rows of text (mat=0) or opin (mat=1).
// MFMA GEMM rows@W^T (fp16 in, fp32 acc). Wave (rg = 16-row grp, nh = n-half).
// mat=1 emits V^T fp16: vtg[(b*256+h)*2048 + j].
// launch_bounds (256,2): 256-VGPR budget — no spill risk (wreg+acc+vals ~110).
// ---------------------------------------------------------------------------
__global__ __launch_bounds__(256, 2) void prep_kernel(
    const float* __restrict__ opin, const float* __restrict__ text,
    const int* __restrict__ pos_ids,
    const float* __restrict__ Wt, const float* __restrict__ bt,
    const float* __restrict__ Wo, const float* __restrict__ wa,
    const float* __restrict__ ba,
    float* __restrict__ ws_st, float2* __restrict__ ws_cm,
    _Float16* __restrict__ vtg)
{
    __shared__ __align__(16) _Float16 a_lds[2][8][512];   // [rg][kc][frag] 16 KB
    __shared__ __align__(16) _Float16 w_lds[16][512];     // 16 KB, single buffer
    __shared__ float red[2][2][16];                       // [nh][rg][row16]

    const int tid  = threadIdx.x;
    const int lane = tid & 63;
    const int wid  = tid >> 6;
    const int rg   = wid & 1;
    const int nh   = wid >> 1;
    const int em   = lane & 15, quad = lane >> 4;
    const int mat  = blockIdx.x & 1;
    const size_t g0 = (size_t)(blockIdx.x >> 1) * 32;

    const float* __restrict__ src = mat ? opin : text;
    const float* __restrict__ W   = mat ? Wo   : Wt;

    // ---- stage A: 32 rows x 256 k, fp32->fp16, frag-linear ----
#pragma unroll
    for (int i = 0; i < 4; ++i) {
        const int idx = i * 256 + tid;
        const int row = idx >> 5;
        const int k   = (idx & 31) * 8;
        const float4 f0 = *(const float4*)(src + (g0 + row) * 256 + k);
        const float4 f1 = *(const float4*)(src + (g0 + row) * 256 + k + 4);
        half8 h = { (_Float16)f0.x, (_Float16)f0.y, (_Float16)f0.z, (_Float16)f0.w,
                    (_Float16)f1.x, (_Float16)f1.y, (_Float16)f1.z, (_Float16)f1.w };
        *(half8*)&a_lds[row >> 4][k >> 5][((row & 15) + 16 * ((k >> 3) & 3)) * 8] = h;
    }

    // prefetch W chunk 0
    float4 wreg[8];
#pragma unroll
    for (int i = 0; i < 4; ++i) {
        const int idx = i * 256 + tid;
        const int n = idx >> 2, ko = (idx & 3) * 8;
        wreg[2 * i]     = *(const float4*)(W + n * 256 + ko);
        wreg[2 * i + 1] = *(const float4*)(W + n * 256 + ko + 4);
    }
    __syncthreads();   // a_lds ready

    f32x4 acc[8];
#pragma unroll
    for (int nt = 0; nt < 8; ++nt) acc[nt] = (f32x4){0.f, 0.f, 0.f, 0.f};

    for (int kc = 0; kc < 8; ++kc) {
        // write prefetched W chunk (fp16, frag-linear)
#pragma unroll
        for (int i = 0; i < 4; ++i) {
            const int idx = i * 256 + tid;
            const int n = idx >> 2, ko = (idx & 3) * 8;
            const float4 a = wreg[2 * i], c = wreg[2 * i + 1];
            half8 h = { (_Float16)a.x, (_Float16)a.y, (_Float16)a.z, (_Float16)a.w,
                        (_Float16)c.x, (_Float16)c.y, (_Float16)c.z, (_Float16)c.w };
            *(half8*)&w_lds[n >> 4][((n & 15) + 16 * (ko >> 3)) * 8] = h;
        }
        __syncthreads();   // w_lds ready
        if (kc < 7) {
#pragma unroll
            for (int i = 0; i < 4; ++i) {
                const int idx = i * 256 + tid;
                const int n = idx >> 2, ko = (idx & 3) * 8;
                wreg[2 * i]     = *(const float4*)(W + n * 256 + (kc + 1) * 32 + ko);
                wreg[2 * i + 1] = *(const float4*)(W + n * 256 + (kc + 1) * 32 + ko + 4);
            }
        }
        const half8 af = *(const half8*)&a_lds[rg][kc][lane * 8];
#pragma unroll
        for (int nt = 0; nt < 8; ++nt) {
            const half8 bf = *(const half8*)&w_lds[nh * 8 + nt][lane * 8];
            acc[nt] = __builtin_amdgcn_mfma_f32_16x16x32_f16(af, bf, acc[nt], 0, 0, 0);
        }
        __syncthreads();   // all reads done before next overwrite
    }

    // ---- epilogue: rowsum_n( tanh(acc + bt?) * wa ) over this wave's n-half ----
    float rowsum[4] = {0.f, 0.f, 0.f, 0.f};
#pragma unroll
    for (int nt = 0; nt < 8; ++nt) {
        const int col  = nh * 128 + nt * 16 + em;
        const float btv = mat ? 0.f : bt[col];
        const float wav = wa[mat * 256 + col];
#pragma unroll
        for (int r = 0; r < 4; ++r)
            rowsum[r] += fast_tanh(acc[nt][r] + btv) * wav;
    }
#pragma unroll
    for (int r = 0; r < 4; ++r) {
        float s = rowsum[r];
        s += __shfl_xor(s, 1, 64);
        s += __shfl_xor(s, 2, 64);
        s += __shfl_xor(s, 4, 64);
        s += __shfl_xor(s, 8, 64);
        if (em == 0) red[nh][rg][quad * 4 + r] = s;
    }
    __syncthreads();

    if (tid < 32) {
        const float s = red[0][tid >> 4][tid & 15] + red[1][tid >> 4][tid & 15];
        const size_t grow = g0 + tid;
        if (mat == 0) {
            ws_st[grow] = s;
        } else {
            const int p = pos_ids[grow];
            const bool isop = (p==19)|(p==20)|(p==21)|(p==33)|(p==34)|(p==35)|((p>=41)&(p<=46));
            const float mult = isop ? 8.f : 1.f;
            ws_cm[grow] = make_float2((s + ba[0]) * mult, mult);
        }
    }

    // ---- V^T emission (opin blocks): vtg[(b*256+h)*2048 + j] ----
    if (mat == 1) {
        const int h = tid;
        const int kcS = h >> 5, kq = (h >> 3) & 3, jh = h & 7;
        _Float16 vals[32];
#pragma unroll
        for (int r = 0; r < 32; ++r)
            vals[r] = a_lds[r >> 4][kcS][((r & 15) + 16 * kq) * 8 + jh];
        _Float16* dst = vtg + ((size_t)((g0 >> 11) * 256 + h)) * 2048 + (g0 & 2047);
#pragma unroll
        for (int w = 0; w < 4; ++w)
            *(half8*)(dst + w * 8) = *(half8*)&vals[w * 8];
    }
}

// ---------------------------------------------------------------------------
// attn: 256 blocks = (b, 64-row tile), 512 thr. WAVE-SPECIALIZED:
//   waves 0-3 (producers): scores for chunk k+1 in MFMA A-layout -> dbuf p_lds.
//   waves 4-7 (consumers): af from p_lds + bf DIRECT FROM GLOBAL (register
//     dbuf, prefetched 1 chunk ahead) + 32 MFMA for chunk k.
// K-loop unrolled x2 so BUF is a compile-time literal -> bfr[] stays in
// registers (R6's runtime `buf` demoted bfr to scratch: 155 MB WRITE_SIZE).
// ---------------------------------------------------------------------------
__global__ __launch_bounds__(512, 2) void attn_kernel(
    const float* __restrict__ ws_st, const float2* __restrict__ ws_cm,
    const _Float16* __restrict__ vtg, float* __restrict__ out)
{
    __shared__ __align__(16) _Float16 p_lds[2][4][2][512];  // [buf][rt][ks][frag]
    __shared__ float m_tbl[64];
    __shared__ float zrow[64];

    const int tid  = threadIdx.x;
    const int lane = tid & 63;
    const int wid  = tid >> 6;
    const int em   = lane & 15, quad = lane >> 4;
    const int b    = blockIdx.x & 7;          // batch -> XCD L2 locality
    const int i0   = (blockIdx.x >> 3) * 64;

    const bool producer = (wid < 4);
    const int cw = wid - 4;                   // consumer h-quarter

    const _Float16* __restrict__ vb = vtg + (size_t)(b * 256) * 2048;

    // consumer: issue bf(0) prefetch before prepass (latency hidden)
    half8 bfr[2][8];
    if (!producer) {
#pragma unroll
        for (int ht = 0; ht < 4; ++ht)
#pragma unroll
            for (int ks = 0; ks < 2; ++ks) {
                const int h = cw * 64 + ht * 16 + em;
                const int j = ks * 32 + quad * 8;
                bfr[0][ht * 2 + ks] = *(const half8*)(vb + (size_t)h * 2048 + j);
            }
    }

    // ---- exact row-max prepass (all 8 waves; dup-free) ----
    {
        const int prow = wid * 8 + (lane >> 3);
        const int gi_p = i0 + prow;
        const float st_p = ws_st[b * 2048 + gi_p];
        const int jg = (lane & 7) * 8;
        float mx = -3.0e38f;
        for (int t = 0; t < 32; ++t) {
            const int j = t * 64 + jg;
            const float4* cmp = (const float4*)(ws_cm + (size_t)b * 2048 + j);
            const float4 c01 = cmp[0], c23 = cmp[1], c45 = cmp[2], c67 = cmp[3];
            const float cmm[8] = {c01.x, c01.z, c23.x, c23.z, c45.x, c45.z, c67.x, c67.z};
            const float mm[8]  = {c01.y, c01.w, c23.y, c23.w, c45.y, c45.w, c67.y, c67.w};
#pragma unroll
            for (int e = 0; e < 8; ++e) {
                int d = gi_p - (j + e); d = d < 0 ? -d : d;
                mx = fmaxf(mx, score_arg(st_p, cmm[e], mm[e], d));
            }
        }
        mx = fmaxf(mx, __shfl_xor(mx, 1, 64));
        mx = fmaxf(mx, __shfl_xor(mx, 2, 64));
        mx = fmaxf(mx, __shfl_xor(mx, 4, 64));
        if ((lane & 7) == 0) m_tbl[prow] = mx;
    }
    __syncthreads();   // m_tbl ready

    // producer row constants (wave wid owns rows wid*16..+15, lane row = em)
    float st_r = 0.f, mp = 0.f;
    int gi = 0;
    if (producer) {
        const int row = wid * 16 + em;
        gi   = i0 + row;
        st_r = ws_st[b * 2048 + gi];
        mp   = m_tbl[row];
    }
    float zacc = 0.f;

    // producer: compute scores for chunk `kchunk` into p_lds[pbuf][wid][ks]
    auto produce = [&](int kchunk, int pbuf) {
        const int j0 = kchunk * 64;
#pragma unroll
        for (int ks = 0; ks < 2; ++ks) {
            const int jb = j0 + ks * 32 + quad * 8;
            const float4* cmp = (const float4*)(ws_cm + (size_t)b * 2048 + jb);
            const float4 c01 = cmp[0], c23 = cmp[1], c45 = cmp[2], c67 = cmp[3];
            const float cmm[8] = {c01.x, c01.z, c23.x, c23.z, c45.x, c45.z, c67.x, c67.z};
            const float mm[8]  = {c01.y, c01.w, c23.y, c23.w, c45.y, c45.w, c67.y, c67.w};
            const int c0 = gi - jb;
            half8 pv;
#pragma unroll
            for (int e = 0; e < 8; ++e) {
                int d = c0 - e; d = d < 0 ? -d : d;
                const float p = __builtin_exp2f(score_arg(st_r, cmm[e], mm[e], d) - mp);
                zacc += p;
                pv[e] = (_Float16)p;
            }
            *(half8*)&p_lds[pbuf][wid][ks][lane * 8] = pv;
        }
    };

    if (producer) produce(0, 0);
    __syncthreads();   // p_lds[0] ready

    f32x4 acc[4][4];
#pragma unroll
    for (int rt = 0; rt < 4; ++rt)
#pragma unroll
        for (int ht = 0; ht < 4; ++ht) acc[rt][ht] = (f32x4){0.f, 0.f, 0.f, 0.f};

    // ---- main loop, unrolled x2: BUF is a literal (bfr stays in VGPRs) ----
#define ATTN_STEP(KC, BUF)                                                       \
    {                                                                            \
        if (producer) {                                                          \
            if ((KC) < 31) produce((KC) + 1, (BUF) ^ 1);                         \
        } else {                                                                 \
            if ((KC) < 31) {                                                     \
                _Pragma("unroll")                                                \
                for (int ht = 0; ht < 4; ++ht) {                                 \
                    _Pragma("unroll")                                            \
                    for (int ks = 0; ks < 2; ++ks) {                             \
                        const int h = cw * 64 + ht * 16 + em;                    \
                        const int j = ((KC) + 1) * 64 + ks * 32 + quad * 8;      \
                        bfr[(BUF) ^ 1][ht * 2 + ks] =                            \
                            *(const half8*)(vb + (size_t)h * 2048 + j);          \
                    }                                                            \
                }                                                                \
            }                                                                    \
            half8 af[4][2];                                                      \
            _Pragma("unroll")                                                    \
            for (int rt = 0; rt < 4; ++rt) {                                     \
                _Pragma("unroll")                                                \
                for (int ks = 0; ks < 2; ++ks)                                   \
                    af[rt][ks] = *(const half8*)&p_lds[BUF][rt][ks][lane * 8];   \
            }                                                                    \
            _Pragma("unroll")                                                    \
            for (int ks = 0; ks < 2; ++ks) {                                     \
                _Pragma("unroll")                                                \
                for (int ht = 0; ht < 4; ++ht) {                                 \
                    const half8 bf = bfr[BUF][ht * 2 + ks];                      \
                    _Pragma("unroll")                                            \
                    for (int rt = 0; rt < 4; ++rt)                               \
                        acc[rt][ht] = __builtin_amdgcn_mfma_f32_16x16x32_f16(    \
                            af[rt][ks], bf, acc[rt][ht], 0, 0, 0);               \
                }                                                                \
            }                                                                    \
        }                                                                        \
        __syncthreads();                                                         \
    }

    for (int kk = 0; kk < 16; ++kk) {
        const int kc0 = kk * 2;
        ATTN_STEP(kc0, 0);
        ATTN_STEP(kc0 + 1, 1);
    }
#undef ATTN_STEP

    // ---- Z finalize (producers own rows) ----
    if (producer) {
        zacc += __shfl_xor(zacc, 16, 64);
        zacc += __shfl_xor(zacc, 32, 64);
        if (quad == 0) zrow[wid * 16 + em] = zacc;
    }
    __syncthreads();

    // ---- epilogue (consumers): C/D row = quad*4+reg, col = em ----
    if (!producer) {
#pragma unroll
        for (int rt = 0; rt < 4; ++rt) {
#pragma unroll
            for (int r = 0; r < 4; ++r) {
                const int rloc = rt * 16 + quad * 4 + r;
                const float rz = 1.0f / zrow[rloc];
                float* op = out + ((size_t)b * 2048 + (i0 + rloc)) * 256 + cw * 64 + em;
#pragma unroll
                for (int ht = 0; ht < 4; ++ht)
                    op[ht * 16] = acc[rt][ht][r] * rz;
            }
        }
    }
}

// ---------------------------------------------------------------------------
extern "C" void kernel_launch(void* const* d_in, const int* in_sizes, int n_in,
                              void* d_out, int out_size, void* d_ws, size_t ws_size,
                              hipStream_t stream) {
    const float* opin  = (const float*)d_in[0];
    const float* text  = (const float*)d_in[1];
    const int* pos_ids = (const int*)d_in[2];
    const float* Wt    = (const float*)d_in[3];
    const float* bt    = (const float*)d_in[4];
    const float* Wo    = (const float*)d_in[5];
    const float* wa    = (const float*)d_in[6];
    const float* ba    = (const float*)d_in[7];
    float* out         = (float*)d_out;

    // workspace: st (64 KB) | cm (128 KB) | vtg fp16 [b*256+h][2048] (8 MB)
    float*  ws_st = (float*)d_ws;
    float2* ws_cm = (float2*)((char*)d_ws + 65536);
    _Float16* vtg = (_Float16*)((char*)d_ws + 65536 + 131072);

    prep_kernel<<<1024, 256, 0, stream>>>(opin, text, pos_ids, Wt, bt, Wo, wa, ba,
                                          ws_st, ws_cm, vtg);
    attn_kernel<<<256, 512, 0, stream>>>(ws_st, ws_cm, vtg, out);
}